// Round 1
// baseline (147.051 us; speedup 1.0000x reference)
//
#include <hip/hip_runtime.h>

// Problem constants
constexpr int T_    = 4096;
constexpr int DH_   = 128;
constexpr int NB_   = 32;    // buckets
constexpr int BSZ_  = 128;   // bucket size
constexpr int HH_   = 4;     // H/2 (rotated heads start here)
constexpr int H_    = 8;
constexpr int BH_   = 32;    // B*H

typedef __attribute__((ext_vector_type(8))) short short8;
typedef __attribute__((ext_vector_type(4))) float f32x4;

__device__ __forceinline__ unsigned short f2bf(float f) {
  // round-to-nearest-even fp32 -> bf16 (finite inputs only)
  unsigned int u = __float_as_uint(f);
  unsigned int r = (u + 0x7FFFu + ((u >> 16) & 1u)) >> 16;
  return (unsigned short)r;
}

// ---------------- Kernel A1: per-bucket column sums + first row of each bucket ----------
__global__ void k_bucket_sums(const float* __restrict__ k,
                              float* __restrict__ bucketsum,
                              float* __restrict__ firstrow) {
  int blk = blockIdx.x;           // (b*H + h)*NB + u
  int u = blk & (NB_ - 1);
  int bh = blk >> 5;
  int h = bh & (H_ - 1);
  bool rot = (h >= HH_);
  int d = threadIdx.x;            // 0..127
  const float* kb = k + (size_t)bh * T_ * DH_;
  float acc = 0.f, first = 0.f;
  for (int i = 0; i < BSZ_; ++i) {
    int t = u * BSZ_ + i;
    if (rot) t = (t + (BSZ_ - 1)) & (T_ - 1);
    float val = kb[(size_t)t * DH_ + d];
    if (i == 0) first = val;
    acc += val;
  }
  bucketsum[(size_t)blk * DH_ + d] = acc;
  firstrow [(size_t)blk * DH_ + d] = first;
}

// ---------------- Kernel A2: routing matrix R -> (scale, idx) per bucket ----------------
__global__ void k_routing(const float* __restrict__ W,
                          const float* __restrict__ bucketsum,
                          const float* __restrict__ firstrow,
                          float* __restrict__ scaleArr,
                          int* __restrict__ idxArr) {
  __shared__ float Wl[2 * DH_ * NB_];      // [e][v] row-major, 8192 floats
  __shared__ float Xl[NB_][2 * DH_ + 1];   // padded to kill bank conflicts
  int bh = blockIdx.x;
  int h = bh & (H_ - 1);
  int tid = threadIdx.x;                   // 256 threads

  for (int i = tid; i < 2 * DH_ * NB_; i += 256)
    Wl[i] = W[(size_t)h * 2 * DH_ * NB_ + i];

  if (tid < DH_) {
    int d = tid;
    float S = 0.f;
    for (int u = 0; u < NB_; ++u) {
      float fr = firstrow [((size_t)bh * NB_ + u) * DH_ + d];
      float bs = bucketsum[((size_t)bh * NB_ + u) * DH_ + d];
      Xl[u][d]        = (S + fr) / (float)(u * BSZ_ + 1);  // running mean at bucket start
      Xl[u][DH_ + d]  = fr;                                 // raw k at bucket start
      S += bs;
    }
  }
  __syncthreads();

  if (tid < NB_) {
    int u = tid;
    float r[NB_];
    #pragma unroll
    for (int v = 0; v < NB_; ++v) r[v] = 0.f;
    for (int e = 0; e < 2 * DH_; ++e) {
      float xv = Xl[u][e];
      #pragma unroll
      for (int v = 0; v < NB_; ++v) r[v] += xv * Wl[e * NB_ + v];
    }
    float m = -3.4e38f;
    #pragma unroll
    for (int v = 0; v < NB_; ++v) {
      r[v] = (r[v] > 0.f) ? r[v] : 0.01f * r[v];   // leaky relu
      m = fmaxf(m, r[v]);
    }
    float Z = 0.f;
    #pragma unroll
    for (int v = 0; v < NB_; ++v) Z += expf(r[v] - m);
    float best = -3.4e38f; int bi = 0;
    for (int v = 0; v < u; ++v) {        // tril(-1): only v < u survive
      if (r[v] > best) { best = r[v]; bi = v; }
    }
    float sc = (u == 0) ? 0.f : expf(best - m) / Z;
    scaleArr[bh * NB_ + u] = sc;
    idxArr  [bh * NB_ + u] = (u == 0) ? 0 : bi;
  }
}

// ---------------- Kernel B: bucketed attention with MFMA bf16 --------------------------
__global__ __launch_bounds__(512, 2)
void k_attn(const float* __restrict__ q, const float* __restrict__ k,
            const float* __restrict__ v, const float* __restrict__ scaleArr,
            const int* __restrict__ idxArr, float* __restrict__ out) {
  // K2: 256 rows (j) x 128 cols (d) bf16, row stride 256B. Reused as P: 128 rows (i) x 256 (j), stride 512B.
  // VT: 128 rows (d) x 256 cols (j) bf16, row stride 512B.
  __shared__ unsigned short K2[256 * 128];
  __shared__ unsigned short VT[128 * 256];

  int blk = blockIdx.x;
  int u  = blk & (NB_ - 1);
  int bh = blk >> 5;
  int h  = bh & (H_ - 1);
  bool rot = (h >= HH_);
  float sc = scaleArr[bh * NB_ + u];
  int  src = idxArr  [bh * NB_ + u];
  const size_t base = (size_t)bh * T_ * DH_;

  int tid  = threadIdx.x;
  int lane = tid & 63;
  int w    = tid >> 6;        // wave 0..7, owns q-rows [16w, 16w+16)
  int g    = lane >> 4;       // 0..3
  int c    = lane & 15;       // 0..15

  // ---- Q fragments: global -> registers (A-frag: row=c, k = 32*kt + 8*g + jj) ----
  short8 qf[4];
  {
    int t = u * BSZ_ + 16 * w + c;
    if (rot) t = (t + (BSZ_ - 1)) & (T_ - 1);
    const float* qrow = q + base + (size_t)t * DH_;
    #pragma unroll
    for (int kt = 0; kt < 4; ++kt) {
      int d0 = kt * 32 + g * 8;
      float4 a = *(const float4*)(qrow + d0);
      float4 b = *(const float4*)(qrow + d0 + 4);
      short8 f;
      f[0] = (short)f2bf(a.x); f[1] = (short)f2bf(a.y);
      f[2] = (short)f2bf(a.z); f[3] = (short)f2bf(a.w);
      f[4] = (short)f2bf(b.x); f[5] = (short)f2bf(b.y);
      f[6] = (short)f2bf(b.z); f[7] = (short)f2bf(b.w);
      qf[kt] = f;
    }
  }

  // ---- Stage K2 = [sc*k[src], k[u]] (bf16, swizzled) ----
  #pragma unroll
  for (int rep = 0; rep < 16; ++rep) {
    int chunk = tid + rep * 512;          // 8192 chunks of 4 floats
    int jr = chunk >> 5;                  // 0..255
    int c0 = (chunk & 31) * 4;            // 0..124
    int t; float mul;
    if (jr < BSZ_) { t = src * BSZ_ + jr;          mul = sc;  }
    else           { t = u   * BSZ_ + (jr - BSZ_); mul = 1.f; }
    if (rot) t = (t + (BSZ_ - 1)) & (T_ - 1);
    float4 a = *(const float4*)(k + base + (size_t)t * DH_ + c0);
    ushort4 wv;
    wv.x = f2bf(a.x * mul); wv.y = f2bf(a.y * mul);
    wv.z = f2bf(a.z * mul); wv.w = f2bf(a.w * mul);
    int byteoff = jr * 256 + ((c0 * 2) ^ ((jr & 15) << 4));
    *(ushort4*)((char*)K2 + byteoff) = wv;
  }

  // ---- Stage VT = transpose of [sc*v[src], v[u]] (bf16, swizzled) via 4x4 micro-transpose ----
  #pragma unroll
  for (int rep = 0; rep < 4; ++rep) {
    int chunk = tid + rep * 512;          // 2048 4x4 tiles
    int dt  = chunk & 31;                 // d tile
    int jt4 = chunk >> 5;                 // j tile
    int d0 = dt * 4, j0 = jt4 * 4;
    float rr[4][4];
    #pragma unroll
    for (int jj = 0; jj < 4; ++jj) {
      int j = j0 + jj;
      int t; float mul;
      if (j < BSZ_) { t = src * BSZ_ + j;          mul = sc;  }
      else          { t = u   * BSZ_ + (j - BSZ_); mul = 1.f; }
      if (rot) t = (t + (BSZ_ - 1)) & (T_ - 1);
      float4 a = *(const float4*)(v + base + (size_t)t * DH_ + d0);
      rr[jj][0] = a.x * mul; rr[jj][1] = a.y * mul;
      rr[jj][2] = a.z * mul; rr[jj][3] = a.w * mul;
    }
    #pragma unroll
    for (int m = 0; m < 4; ++m) {
      ushort4 wv;
      wv.x = f2bf(rr[0][m]); wv.y = f2bf(rr[1][m]);
      wv.z = f2bf(rr[2][m]); wv.w = f2bf(rr[3][m]);
      int row = d0 + m;
      int byteoff = row * 512 + ((j0 * 2) ^ ((row & 15) << 4));
      *(ushort4*)((char*)VT + byteoff) = wv;
    }
  }
  __syncthreads();

  // ---- QK^T: dots tile 16 rows x 256 cols per wave ----
  f32x4 acc[16];
  #pragma unroll
  for (int jt = 0; jt < 16; ++jt) acc[jt] = f32x4{0.f, 0.f, 0.f, 0.f};

  #pragma unroll
  for (int kt = 0; kt < 4; ++kt) {
    #pragma unroll
    for (int jt = 0; jt < 16; ++jt) {
      int row = jt * 16 + c;
      int byteoff = row * 256 + ((kt * 64 + g * 16) ^ ((row & 15) << 4));
      short8 bfr = *(const short8*)((const char*)K2 + byteoff);
      acc[jt] = __builtin_amdgcn_mfma_f32_16x16x32_bf16(qf[kt], bfr, acc[jt], 0, 0, 0);
    }
  }

  __syncthreads();   // all K2 reads done before we overwrite it with P

  // ---- mask + softmax (row-wise over 256) + write P (bf16) into K2 space ----
  const bool lastrot = rot && (u == NB_ - 1);
  #pragma unroll
  for (int r = 0; r < 4; ++r) {
    int i = 16 * w + 4 * g + r;       // row within bucket (0..127)
    float mx = -3.4e38f;
    #pragma unroll
    for (int jt = 0; jt < 16; ++jt) {
      int j = jt * 16 + c;
      float s = acc[jt][r] * 0.03125f;   // * d^-0.5, d=1024
      bool causal = (j < BSZ_) || (i >= j - BSZ_);
      bool vis;
      if (lastrot) {
        bool special = (j <= BSZ_) && (i > 0);
        vis = causal && !special;
      } else vis = causal;
      s = vis ? s : -3.4e38f;
      acc[jt][r] = s;
      mx = fmaxf(mx, s);
    }
    mx = fmaxf(mx, __shfl_xor(mx, 1));
    mx = fmaxf(mx, __shfl_xor(mx, 2));
    mx = fmaxf(mx, __shfl_xor(mx, 4));
    mx = fmaxf(mx, __shfl_xor(mx, 8));
    float zs = 0.f;
    #pragma unroll
    for (int jt = 0; jt < 16; ++jt) {
      float p = expf(acc[jt][r] - mx);
      acc[jt][r] = p;
      zs += p;
    }
    zs += __shfl_xor(zs, 1);
    zs += __shfl_xor(zs, 2);
    zs += __shfl_xor(zs, 4);
    zs += __shfl_xor(zs, 8);
    float rz = 1.f / zs;
    #pragma unroll
    for (int jt = 0; jt < 16; ++jt) {
      float p = acc[jt][r] * rz;
      int j = jt * 16 + c;
      int byteoff = i * 512 + ((j * 2) ^ ((i & 15) << 4));
      *(unsigned short*)((char*)K2 + byteoff) = f2bf(p);
    }
  }

  // ---- PV: out tile 16 rows x 128 cols per wave ----
  f32x4 o[8];
  #pragma unroll
  for (int nt = 0; nt < 8; ++nt) o[nt] = f32x4{0.f, 0.f, 0.f, 0.f};

  #pragma unroll
  for (int kt = 0; kt < 8; ++kt) {
    int prow = 16 * w + c;
    int pbyte = prow * 512 + ((kt * 64 + g * 16) ^ ((prow & 15) << 4));
    short8 pa = *(const short8*)((const char*)K2 + pbyte);
    #pragma unroll
    for (int nt = 0; nt < 8; ++nt) {
      int vrow = nt * 16 + c;
      int vbyte = vrow * 512 + ((kt * 64 + g * 16) ^ ((vrow & 15) << 4));
      short8 vb = *(const short8*)((const char*)VT + vbyte);
      o[nt] = __builtin_amdgcn_mfma_f32_16x16x32_bf16(pa, vb, o[nt], 0, 0, 0);
    }
  }

  // ---- store (undo rotation on the way out) ----
  #pragma unroll
  for (int r = 0; r < 4; ++r) {
    int il = 4 * g + r;
    int t = u * BSZ_ + 16 * w + il;
    if (rot) t = (t + (BSZ_ - 1)) & (T_ - 1);
    float* orow = out + base + (size_t)t * DH_;
    #pragma unroll
    for (int nt = 0; nt < 8; ++nt) {
      orow[nt * 16 + c] = o[nt][r];
    }
  }
}

extern "C" void kernel_launch(void* const* d_in, const int* in_sizes, int n_in,
                              void* d_out, int out_size, void* d_ws, size_t ws_size,
                              hipStream_t stream) {
  const float* q = (const float*)d_in[0];
  const float* k = (const float*)d_in[1];
  const float* v = (const float*)d_in[2];
  const float* W = (const float*)d_in[3];
  float* out = (float*)d_out;

  float* bucketsum = (float*)d_ws;               // 32*32*128 = 131072 floats
  float* firstrow  = bucketsum + 131072;         // 131072 floats
  float* scaleArr  = firstrow + 131072;          // 1024 floats
  int*   idxArr    = (int*)(scaleArr + 1024);    // 1024 ints

  k_bucket_sums<<<BH_ * NB_, DH_, 0, stream>>>(k, bucketsum, firstrow);
  k_routing<<<BH_, 256, 0, stream>>>(W, bucketsum, firstrow, scaleArr, idxArr);
  k_attn<<<BH_ * NB_, 512, 0, stream>>>(q, k, v, scaleArr, idxArr, out);
}

// Round 2
// 92.094 us; speedup vs baseline: 1.5967x; 1.5967x over previous
//
#include <hip/hip_runtime.h>

// Problem constants
constexpr int T_    = 4096;
constexpr int DH_   = 128;
constexpr int NB_   = 32;    // buckets
constexpr int BSZ_  = 128;   // bucket size
constexpr int HH_   = 4;     // H/2 (rotated heads start here)
constexpr int H_    = 8;
constexpr int BH_   = 32;    // B*H

typedef __attribute__((ext_vector_type(8))) short short8;
typedef __attribute__((ext_vector_type(4))) float f32x4;

__device__ __forceinline__ unsigned short f2bf(float f) {
  // round-to-nearest-even fp32 -> bf16 (finite inputs only)
  unsigned int u = __float_as_uint(f);
  unsigned int r = (u + 0x7FFFu + ((u >> 16) & 1u)) >> 16;
  return (unsigned short)r;
}

// ---------------- Kernel A1: per-bucket column sums + first row of each bucket ----------
// 256 threads: 8 row-groups x 32 lanes (float4 over d). 16 float4 loads/thread.
__global__ __launch_bounds__(256)
void k_bucket_sums(const float* __restrict__ k,
                   float* __restrict__ bucketsum,
                   float* __restrict__ firstrow) {
  __shared__ float4 red[8][32];
  int blk = blockIdx.x;           // (b*H + h)*NB + u
  int u = blk & (NB_ - 1);
  int bh = blk >> 5;
  int h = bh & (H_ - 1);
  bool rot = (h >= HH_);
  int tid = threadIdx.x;
  int rq = tid >> 5;              // 0..7
  int l  = tid & 31;              // 0..31
  int d0 = l * 4;
  const float* kb = k + (size_t)bh * T_ * DH_;

  float4 s = {0.f, 0.f, 0.f, 0.f};
  float4 first = {0.f, 0.f, 0.f, 0.f};
  #pragma unroll
  for (int it = 0; it < 16; ++it) {
    int i = it * 8 + rq;
    int t = u * BSZ_ + i;
    if (rot) t = (t + (BSZ_ - 1)) & (T_ - 1);
    float4 a = *(const float4*)(kb + (size_t)t * DH_ + d0);
    s.x += a.x; s.y += a.y; s.z += a.z; s.w += a.w;
    if (it == 0 && rq == 0) first = a;
  }
  red[rq][l] = s;
  __syncthreads();
  if (rq == 0) {
    float4 acc = {0.f, 0.f, 0.f, 0.f};
    #pragma unroll
    for (int j = 0; j < 8; ++j) {
      float4 a = red[j][l];
      acc.x += a.x; acc.y += a.y; acc.z += a.z; acc.w += a.w;
    }
    *(float4*)(bucketsum + (size_t)blk * DH_ + d0) = acc;
    *(float4*)(firstrow  + (size_t)blk * DH_ + d0) = first;
  }
}

// ---------------- Kernel A2: routing matrix R -> (scale, idx) per bucket ----------------
__global__ __launch_bounds__(256)
void k_routing(const float* __restrict__ W,
               const float* __restrict__ bucketsum,
               const float* __restrict__ firstrow,
               float* __restrict__ scaleArr,
               int* __restrict__ idxArr) {
  __shared__ float Wl[2 * DH_ * NB_];      // [e][v] row-major, 8192 floats
  __shared__ float Xl[NB_][2 * DH_ + 1];   // padded
  __shared__ float Rl[NB_][36];            // 36-float rows: 16B aligned
  int bh = blockIdx.x;
  int h = bh & (H_ - 1);
  int tid = threadIdx.x;                   // 256 threads

  const float4* Wg = (const float4*)(W + (size_t)h * 2 * DH_ * NB_);
  #pragma unroll
  for (int rep = 0; rep < 8; ++rep)
    ((float4*)Wl)[tid + rep * 256] = Wg[tid + rep * 256];

  if (tid < DH_) {
    int d = tid;
    float S = 0.f;
    for (int u = 0; u < NB_; ++u) {
      float fr = firstrow [((size_t)bh * NB_ + u) * DH_ + d];
      float bs = bucketsum[((size_t)bh * NB_ + u) * DH_ + d];
      Xl[u][d]        = (S + fr) / (float)(u * BSZ_ + 1);
      Xl[u][DH_ + d]  = fr;
      S += bs;
    }
  }
  __syncthreads();

  // R = leaky_relu(X W): thread (u, vg) computes 4 dots of length 256
  {
    int u = tid >> 3;
    int vg = tid & 7;
    float4 racc = {0.f, 0.f, 0.f, 0.f};
    for (int e = 0; e < 2 * DH_; ++e) {
      float xv = Xl[u][e];
      float4 wv = *(const float4*)(Wl + e * NB_ + vg * 4);
      racc.x += xv * wv.x; racc.y += xv * wv.y;
      racc.z += xv * wv.z; racc.w += xv * wv.w;
    }
    racc.x = (racc.x > 0.f) ? racc.x : 0.01f * racc.x;
    racc.y = (racc.y > 0.f) ? racc.y : 0.01f * racc.y;
    racc.z = (racc.z > 0.f) ? racc.z : 0.01f * racc.z;
    racc.w = (racc.w > 0.f) ? racc.w : 0.01f * racc.w;
    *(float4*)(&Rl[u][vg * 4]) = racc;
  }
  __syncthreads();

  if (tid < NB_) {
    int u = tid;
    float m = -3.4e38f;
    float r[NB_];
    #pragma unroll
    for (int v = 0; v < NB_; ++v) { r[v] = Rl[u][v]; m = fmaxf(m, r[v]); }
    float Z = 0.f;
    #pragma unroll
    for (int v = 0; v < NB_; ++v) Z += expf(r[v] - m);
    float best = -3.4e38f; int bi = 0;
    for (int v = 0; v < u; ++v) {        // tril(-1): only v < u survive
      if (r[v] > best) { best = r[v]; bi = v; }
    }
    float sc = (u == 0) ? 0.f : expf(best - m) / Z;
    scaleArr[bh * NB_ + u] = sc;
    idxArr  [bh * NB_ + u] = (u == 0) ? 0 : bi;
  }
}

// ---------------- Kernel B: bucketed attention, 64KB LDS -> 2 blocks/CU ----------------
// Two 32KB regions. A: K-half1 -> P-half1 -> P-half2. B: K-half2 -> VT-half1 -> VT-half2.
__global__ __launch_bounds__(512, 4)
void k_attn(const float* __restrict__ q, const float* __restrict__ k,
            const float* __restrict__ v, const float* __restrict__ scaleArr,
            const int* __restrict__ idxArr, float* __restrict__ out) {
  __shared__ unsigned short RA[128 * 128];   // 32KB, row stride 256B
  __shared__ unsigned short RB[128 * 128];   // 32KB

  int blk0 = blockIdx.x;
  int blk  = ((blk0 & 7) << 7) | (blk0 >> 3);  // XCD-chunked swizzle (1024 = 8*128, bijective)
  int u  = blk & (NB_ - 1);
  int bh = blk >> 5;
  int h  = bh & (H_ - 1);
  bool rot = (h >= HH_);
  float sc = scaleArr[bh * NB_ + u];
  int  src = idxArr  [bh * NB_ + u];
  const size_t base = (size_t)bh * T_ * DH_;

  int tid  = threadIdx.x;
  int lane = tid & 63;
  int w    = tid >> 6;        // wave 0..7, owns q-rows [16w, 16w+16)
  int g    = lane >> 4;       // 0..3
  int c    = lane & 15;       // 0..15

  // ---- Q fragments: global -> registers ----
  short8 qf[4];
  {
    int t = u * BSZ_ + 16 * w + c;
    if (rot) t = (t + (BSZ_ - 1)) & (T_ - 1);
    const float* qrow = q + base + (size_t)t * DH_;
    #pragma unroll
    for (int kt = 0; kt < 4; ++kt) {
      int d0 = kt * 32 + g * 8;
      float4 a = *(const float4*)(qrow + d0);
      float4 b = *(const float4*)(qrow + d0 + 4);
      short8 f;
      f[0] = (short)f2bf(a.x); f[1] = (short)f2bf(a.y);
      f[2] = (short)f2bf(a.z); f[3] = (short)f2bf(a.w);
      f[4] = (short)f2bf(b.x); f[5] = (short)f2bf(b.y);
      f[6] = (short)f2bf(b.z); f[7] = (short)f2bf(b.w);
      qf[kt] = f;
    }
  }

  // ---- Stage K halves: A = sc*k[src], B = k[u] (bf16, swizzled) ----
  #pragma unroll
  for (int rep = 0; rep < 16; ++rep) {
    int chunk = tid + rep * 512;          // 8192 chunks of 4 floats
    int jr = chunk >> 5;                  // 0..255
    int c0 = (chunk & 31) * 4;            // 0..124
    int t; float mul; unsigned short* Rg;
    if (jr < BSZ_) { t = src * BSZ_ + jr;         mul = sc;  Rg = RA; }
    else           { t = u  * BSZ_ + (jr - BSZ_); mul = 1.f; Rg = RB; }
    if (rot) t = (t + (BSZ_ - 1)) & (T_ - 1);
    float4 a = *(const float4*)(k + base + (size_t)t * DH_ + c0);
    ushort4 wv;
    wv.x = f2bf(a.x * mul); wv.y = f2bf(a.y * mul);
    wv.z = f2bf(a.z * mul); wv.w = f2bf(a.w * mul);
    int row = jr & 127;
    *(ushort4*)((char*)Rg + row * 256 + ((c0 * 2) ^ ((row & 15) << 4))) = wv;
  }
  __syncthreads();

  // ---- QK^T: 16 rows x 256 cols per wave ----
  f32x4 acc[16];
  #pragma unroll
  for (int jt = 0; jt < 16; ++jt) acc[jt] = f32x4{0.f, 0.f, 0.f, 0.f};

  __builtin_amdgcn_s_setprio(1);
  #pragma unroll
  for (int kt = 0; kt < 4; ++kt) {
    #pragma unroll
    for (int jt = 0; jt < 16; ++jt) {
      const unsigned short* Rg = (jt < 8) ? RA : RB;
      int row = (jt & 7) * 16 + c;
      short8 bfr = *(const short8*)((const char*)Rg + row * 256 + ((kt * 64 + g * 16) ^ (c << 4)));
      acc[jt] = __builtin_amdgcn_mfma_f32_16x16x32_bf16(qf[kt], bfr, acc[jt], 0, 0, 0);
    }
  }
  __builtin_amdgcn_s_setprio(0);

  __syncthreads();   // all K reads done; A,B free for overwrite

  // ---- mask + full-row softmax (in regs) + write P-half1 into A ----
  const bool lastrot = rot && (u == NB_ - 1);
  #pragma unroll
  for (int r = 0; r < 4; ++r) {
    int i = 16 * w + 4 * g + r;
    float mx = -3.4e38f;
    #pragma unroll
    for (int jt = 0; jt < 16; ++jt) {
      int j = jt * 16 + c;
      float s = acc[jt][r] * 0.03125f;   // * d^-0.5, d=1024
      bool causal = (j < BSZ_) || (i >= j - BSZ_);
      bool vis = lastrot ? (causal && !((j <= BSZ_) && (i > 0))) : causal;
      s = vis ? s : -3.4e38f;
      acc[jt][r] = s;
      mx = fmaxf(mx, s);
    }
    mx = fmaxf(mx, __shfl_xor(mx, 1));
    mx = fmaxf(mx, __shfl_xor(mx, 2));
    mx = fmaxf(mx, __shfl_xor(mx, 4));
    mx = fmaxf(mx, __shfl_xor(mx, 8));
    float zs = 0.f;
    #pragma unroll
    for (int jt = 0; jt < 16; ++jt) {
      float p = expf(acc[jt][r] - mx);
      acc[jt][r] = p;
      zs += p;
    }
    zs += __shfl_xor(zs, 1);
    zs += __shfl_xor(zs, 2);
    zs += __shfl_xor(zs, 4);
    zs += __shfl_xor(zs, 8);
    float rz = 1.f / zs;
    #pragma unroll
    for (int jt = 0; jt < 16; ++jt) acc[jt][r] *= rz;
    #pragma unroll
    for (int jt = 0; jt < 8; ++jt) {
      int jc = jt * 16 + c;
      *(unsigned short*)((char*)RA + i * 256 + ((jc * 2) ^ ((i & 15) << 4))) = f2bf(acc[jt][r]);
    }
  }

  // ---- stage VT-half1 = (sc*v[src])^T into B ----
  auto stageVT = [&](int sb, float mul) {
    #pragma unroll
    for (int rep = 0; rep < 2; ++rep) {
      int chunk = tid + rep * 512;        // 1024 4x4 tiles
      int dt = chunk & 31, j4 = chunk >> 5;
      int d0 = dt * 4, j0 = j4 * 4;
      float rr[4][4];
      #pragma unroll
      for (int jj = 0; jj < 4; ++jj) {
        int t = sb * BSZ_ + j0 + jj;
        if (rot) t = (t + (BSZ_ - 1)) & (T_ - 1);
        float4 a = *(const float4*)(v + base + (size_t)t * DH_ + d0);
        rr[jj][0] = a.x * mul; rr[jj][1] = a.y * mul;
        rr[jj][2] = a.z * mul; rr[jj][3] = a.w * mul;
      }
      #pragma unroll
      for (int m = 0; m < 4; ++m) {
        ushort4 wv;
        wv.x = f2bf(rr[0][m]); wv.y = f2bf(rr[1][m]);
        wv.z = f2bf(rr[2][m]); wv.w = f2bf(rr[3][m]);
        int row = d0 + m;
        *(ushort4*)((char*)RB + row * 256 + ((j0 * 2) ^ ((row & 15) << 4))) = wv;
      }
    }
  };
  stageVT(src, sc);
  __syncthreads();

  // ---- PV half: o += P(A) x VT(B) ----
  f32x4 o[8];
  #pragma unroll
  for (int nt = 0; nt < 8; ++nt) o[nt] = f32x4{0.f, 0.f, 0.f, 0.f};

  auto pv = [&]() {
    __builtin_amdgcn_s_setprio(1);
    #pragma unroll
    for (int kt = 0; kt < 4; ++kt) {
      int prow = 16 * w + c;
      short8 pa = *(const short8*)((const char*)RA + prow * 256 + ((kt * 64 + g * 16) ^ (c << 4)));
      #pragma unroll
      for (int nt = 0; nt < 8; ++nt) {
        int vrow = nt * 16 + c;
        short8 vb = *(const short8*)((const char*)RB + vrow * 256 + ((kt * 64 + g * 16) ^ (c << 4)));
        o[nt] = __builtin_amdgcn_mfma_f32_16x16x32_bf16(pa, vb, o[nt], 0, 0, 0);
      }
    }
    __builtin_amdgcn_s_setprio(0);
  };
  pv();   // half 1

  __syncthreads();

  // ---- write P-half2 into A, stage VT-half2 into B ----
  #pragma unroll
  for (int r = 0; r < 4; ++r) {
    int i = 16 * w + 4 * g + r;
    #pragma unroll
    for (int jt = 8; jt < 16; ++jt) {
      int jc = (jt - 8) * 16 + c;
      *(unsigned short*)((char*)RA + i * 256 + ((jc * 2) ^ ((i & 15) << 4))) = f2bf(acc[jt][r]);
    }
  }
  stageVT(u, 1.f);
  __syncthreads();

  pv();   // half 2

  // ---- store (undo rotation on the way out) ----
  #pragma unroll
  for (int r = 0; r < 4; ++r) {
    int il = 4 * g + r;
    int t = u * BSZ_ + 16 * w + il;
    if (rot) t = (t + (BSZ_ - 1)) & (T_ - 1);
    float* orow = out + base + (size_t)t * DH_;
    #pragma unroll
    for (int nt = 0; nt < 8; ++nt) {
      orow[nt * 16 + c] = o[nt][r];
    }
  }
}

extern "C" void kernel_launch(void* const* d_in, const int* in_sizes, int n_in,
                              void* d_out, int out_size, void* d_ws, size_t ws_size,
                              hipStream_t stream) {
  const float* q = (const float*)d_in[0];
  const float* k = (const float*)d_in[1];
  const float* v = (const float*)d_in[2];
  const float* W = (const float*)d_in[3];
  float* out = (float*)d_out;

  float* bucketsum = (float*)d_ws;               // 131072 floats
  float* firstrow  = bucketsum + 131072;         // 131072 floats
  float* scaleArr  = firstrow + 131072;          // 1024 floats
  int*   idxArr    = (int*)(scaleArr + 1024);    // 1024 ints

  k_bucket_sums<<<BH_ * NB_, 256, 0, stream>>>(k, bucketsum, firstrow);
  k_routing<<<BH_, 256, 0, stream>>>(W, bucketsum, firstrow, scaleArr, idxArr);
  k_attn<<<BH_ * NB_, 512, 0, stream>>>(q, k, v, scaleArr, idxArr, out);
}